// Round 11
// baseline (125.909 us; speedup 1.0000x reference)
//
#include <hip/hip_runtime.h>
#include <math.h>

#define BB 256
#define NN 1000
#define DD 128
#define HH 8
#define CC 8            // chunks per batch element
#define RC 125          // rows per chunk
#define NEG -1e9f

__device__ __forceinline__ bool get_mask(const void* m, int flag, size_t idx) {
    if (flag == 1) return ((const int*)m)[idx] != 0;
    if (flag == 2) return ((const float*)m)[idx] != 0.0f;
    return ((const unsigned char*)m)[idx] != 0;
}

// ===========================================================================
// K1: mean partials. grid BB*CC = 2048 blocks (8/CU), 256 thr.
// Pure fp32 stream of X (131 MB). Block 0 also detects mask dtype.
// ===========================================================================
__global__ __launch_bounds__(256) void k_mean(
        const float* __restrict__ X, float* __restrict__ partial,
        const unsigned int* __restrict__ maskw, int* __restrict__ flag) {
    int bid = blockIdx.x, tid = threadIdx.x;
    int b = bid >> 3, ch = bid & 7;
    if (bid == 0 && tid < 64) {
        unsigned int a0 = maskw[tid], a1 = maskw[tid + 64],
                     a2 = maskw[tid + 128], a3 = maskw[tid + 192];
        int ii = (a0 <= 1u) && (a1 <= 1u) && (a2 <= 1u) && (a3 <= 1u);
        int ff = (a0 == 0u || a0 == 0x3F800000u) && (a1 == 0u || a1 == 0x3F800000u) &&
                 (a2 == 0u || a2 == 0x3F800000u) && (a3 == 0u || a3 == 0x3F800000u);
        int ai = __all(ii), af = __all(ff);
        if (tid == 0) *flag = ai ? 1 : (af ? 2 : 0);
    }
    int c = tid & 31, s = tid >> 5;
    const float4* Xr = (const float4*)(X + (size_t)b * NN * DD);
    float4 acc = make_float4(0.f, 0.f, 0.f, 0.f);
    int n0 = ch * RC;
    for (int nl = s; nl < RC; nl += 8) {
        float4 v = Xr[(n0 + nl) * 32 + c];
        acc.x += v.x; acc.y += v.y; acc.z += v.z; acc.w += v.w;
    }
    __shared__ float4 red[8][32];
    red[s][c] = acc;
    __syncthreads();
    for (int st = 4; st >= 1; st >>= 1) {
        if (s < st) {
            float4 o = red[s + st][c];
            red[s][c].x += o.x; red[s][c].y += o.y;
            red[s][c].z += o.z; red[s][c].w += o.w;
        }
        __syncthreads();
    }
    if (s == 0) {
        float4 r = red[0][c];
        float* outp = partial + ((size_t)b * CC + ch) * DD + 4 * c;
        outp[0] = r.x; outp[1] = r.y; outp[2] = r.z; outp[3] = r.w;
    }
}

// ===========================================================================
// K2: per-b query + qk vectors (hoisted out of the chunk kernels).
// grid BB, 256 thr. Writes qkg[b][8][128].
// ===========================================================================
__global__ __launch_bounds__(256) void k_qk(
        const float* __restrict__ X, const float* __restrict__ Wfix,
        const float* __restrict__ Wstep, const float* __restrict__ Wnode,
        const float* __restrict__ partial, const int* __restrict__ prev,
        const int* __restrict__ first, float* __restrict__ qkg) {
    int b = blockIdx.x, tid = threadIdx.x;
    const size_t xoff = (size_t)b * NN * DD;
    __shared__ float ge[DD], sc[2 * DD], qv[DD], qp[2][DD];
    if (tid < DD) {
        float g = 0.f;
        #pragma unroll
        for (int ch = 0; ch < CC; ++ch) g += partial[((size_t)b * CC + ch) * DD + tid];
        ge[tid] = g * (1.0f / NN);
    }
    {
        int src = (tid < DD) ? first[b] : prev[b];
        sc[tid] = X[xoff + (size_t)src * DD + (tid & 127)];
    }
    __syncthreads();
    int p = tid >> 7, d = tid & 127;
    {
        float a = 0.f;
        #pragma unroll 4
        for (int k = p * 64; k < p * 64 + 64; ++k)      a += ge[k] * Wfix[(size_t)k * DD + d];
        #pragma unroll 4
        for (int k = p * 128; k < p * 128 + 128; ++k)   a += sc[k] * Wstep[(size_t)k * DD + d];
        qp[p][d] = a;
    }
    __syncthreads();
    if (tid < DD) qv[tid] = qp[0][tid] + qp[1][tid];
    __syncthreads();
    {
        const float* wrow = Wnode + (size_t)d * 384;
        #pragma unroll
        for (int h = p * 4; h < p * 4 + 4; ++h) {
            const float4* wr = (const float4*)(wrow + h * 16);
            float a = 0.f;
            #pragma unroll
            for (int j4 = 0; j4 < 4; ++j4) {
                float4 w = wr[j4];
                a += w.x * qv[h * 16 + 4 * j4]     + w.y * qv[h * 16 + 4 * j4 + 1]
                   + w.z * qv[h * 16 + 4 * j4 + 2] + w.w * qv[h * 16 + 4 * j4 + 3];
            }
            qkg[((size_t)b * HH + h) * DD + d] = 0.25f * a;   // 1/sqrt(16)
        }
    }
}

// ===========================================================================
// K3: flash chunk: compat(125 rows) -> local masked softmax -> partial PV.
// grid BB*CC = 2048 (8/CU), 256 thr, LDS ~16.5 KB.
// ===========================================================================
__global__ __launch_bounds__(256, 8) void k_flash(
        const float* __restrict__ X, const float* __restrict__ qkg,
        const void* __restrict__ mask, const int* __restrict__ flag,
        float* __restrict__ mqw, float* __restrict__ sqw,
        float* __restrict__ pvp) {
    int bid = blockIdx.x, tid = threadIdx.x;
    int b = bid >> 3, ch = bid & 7;
    const int n0 = ch * RC;
    const size_t xoff = (size_t)b * NN * DD;
    const int f = *flag;

    __shared__ float qk[HH][DD];        // 4 KB
    __shared__ float cm[HH][RC + 3];    // 4 KB
    __shared__ float mloc[HH];
    __shared__ float xp[2][HH][DD];     // 8 KB

    for (int i = tid; i < HH * DD; i += 256)
        qk[i >> 7][i & 127] = qkg[(size_t)b * HH * DD + i];
    __syncthreads();

    // ---- compat: 8 lanes per row, 32 rows per iter ----
    {
        int g = tid & 7, r = tid >> 3;
        #pragma unroll
        for (int it = 0; it < 4; ++it) {
            int nl = it * 32 + r;
            if (it < 3 || nl < RC) {
                int n = n0 + nl;
                const float4* xr = (const float4*)(X + xoff + (size_t)n * DD);
                float acc[HH] = {0.f, 0.f, 0.f, 0.f, 0.f, 0.f, 0.f, 0.f};
                #pragma unroll
                for (int i = 0; i < 4; ++i) {
                    float4 v = xr[g + 8 * i];
                    int col = 4 * (g + 8 * i);
                    #pragma unroll
                    for (int h = 0; h < HH; ++h)
                        acc[h] += v.x * qk[h][col]     + v.y * qk[h][col + 1]
                                + v.z * qk[h][col + 2] + v.w * qk[h][col + 3];
                }
                #pragma unroll
                for (int h = 0; h < HH; ++h) {
                    acc[h] += __shfl_xor(acc[h], 1, 8);
                    acc[h] += __shfl_xor(acc[h], 2, 8);
                    acc[h] += __shfl_xor(acc[h], 4, 8);
                }
                float val = acc[0];
                #pragma unroll
                for (int h = 1; h < HH; ++h) val = (g == h) ? acc[h] : val;
                bool mk = get_mask(mask, f, (size_t)b * NN + n);
                cm[g][nl] = mk ? NEG : val;
            }
        }
    }
    __syncthreads();

    // ---- local max per head (32 lanes/head) ----
    {
        int h = tid >> 5, l = tid & 31;
        float mx = -INFINITY;
        for (int nl = l; nl < RC; nl += 32) mx = fmaxf(mx, cm[h][nl]);
        #pragma unroll
        for (int off = 16; off >= 1; off >>= 1) mx = fmaxf(mx, __shfl_xor(mx, off, 32));
        if (l == 0) mloc[h] = mx;
    }
    __syncthreads();

    // ---- exp + local sum ----
    {
        int h = tid >> 5, l = tid & 31;
        float m_h = mloc[h];
        float sm = 0.f;
        for (int nl = l; nl < RC; nl += 32) {
            float p = __expf(cm[h][nl] - m_h);
            cm[h][nl] = p;
            sm += p;
        }
        #pragma unroll
        for (int off = 16; off >= 1; off >>= 1) sm += __shfl_xor(sm, off, 32);
        if (l == 0) {
            sqw[((size_t)b * CC + ch) * HH + h] = sm;
            mqw[((size_t)b * CC + ch) * HH + h] = m_h;
        }
    }
    __syncthreads();

    // ---- partial PV: 2 row-stripes x 128 d ----
    {
        int s2 = tid >> 7, d = tid & 127;
        float acc[HH] = {0.f, 0.f, 0.f, 0.f, 0.f, 0.f, 0.f, 0.f};
        #pragma unroll 2
        for (int nl = s2; nl < RC; nl += 2) {
            float x = X[xoff + (size_t)(n0 + nl) * DD + d];
            #pragma unroll
            for (int h = 0; h < HH; ++h) acc[h] += cm[h][nl] * x;
        }
        #pragma unroll
        for (int h = 0; h < HH; ++h) xp[s2][h][d] = acc[h];
        __syncthreads();
        if (s2 == 0) {
            #pragma unroll
            for (int h = 0; h < HH; ++h)
                pvp[(((size_t)b * CC + ch) * HH + h) * DD + d] = xp[0][h][d] + xp[1][h][d];
        }
    }
}

// ===========================================================================
// K4: per-b flash-combine -> heads -> glimpse -> gq. grid BB, 256 thr.
// ===========================================================================
__global__ __launch_bounds__(256) void k_comb(
        const float* __restrict__ Wnode, const float* __restrict__ Wout,
        const float* __restrict__ mqw, const float* __restrict__ sqw,
        const float* __restrict__ pvp, float* __restrict__ gqg) {
    int b = blockIdx.x, tid = threadIdx.x;
    __shared__ float wq[CC][HH], Sh[HH];
    __shared__ float xa[HH][DD], qp[2][DD], hd[DD], gl[DD];
    if (tid < HH) {
        float m = mqw[((size_t)b * CC) * HH + tid];
        #pragma unroll
        for (int ch = 1; ch < CC; ++ch)
            m = fmaxf(m, mqw[((size_t)b * CC + ch) * HH + tid]);
        float S = 0.f;
        #pragma unroll
        for (int ch = 0; ch < CC; ++ch) {
            float wgt = __expf(mqw[((size_t)b * CC + ch) * HH + tid] - m);
            wq[ch][tid] = wgt;
            S += sqw[((size_t)b * CC + ch) * HH + tid] * wgt;
        }
        Sh[tid] = 1.0f / S;
    }
    __syncthreads();
    for (int idx = tid; idx < HH * DD; idx += 256) {
        int h = idx >> 7, d = idx & 127;
        float a = 0.f;
        #pragma unroll
        for (int ch = 0; ch < CC; ++ch)
            a += pvp[(((size_t)b * CC + ch) * HH + h) * DD + d] * wq[ch][h];
        xa[h][d] = a * Sh[h];
    }
    __syncthreads();
    int p = tid >> 7, t = tid & 127;
    {
        int h = t >> 4;
        float a = 0.f;
        #pragma unroll 4
        for (int d = p * 64; d < p * 64 + 64; ++d)
            a += xa[h][d] * Wnode[(size_t)d * 384 + 128 + t];
        qp[p][t] = a;
    }
    __syncthreads();
    if (tid < DD) hd[tid] = qp[0][tid] + qp[1][tid];
    __syncthreads();
    {
        float a = 0.f;
        #pragma unroll 4
        for (int k = p * 64; k < p * 64 + 64; ++k) a += hd[k] * Wout[(size_t)k * DD + t];
        qp[p][t] = a;
    }
    __syncthreads();
    if (tid < DD) gl[tid] = qp[0][tid] + qp[1][tid];
    __syncthreads();
    {
        const float4* wr = (const float4*)(Wnode + (size_t)t * 384 + 256 + p * 64);
        float a = 0.f;
        #pragma unroll
        for (int j4 = 0; j4 < 16; ++j4) {
            float4 w = wr[j4];
            int k = p * 64 + 4 * j4;
            a += w.x * gl[k] + w.y * gl[k + 1] + w.z * gl[k + 2] + w.w * gl[k + 3];
        }
        qp[p][t] = a;
    }
    __syncthreads();
    if (tid < DD) gqg[(size_t)b * DD + tid] = (qp[0][tid] + qp[1][tid]) * 0.08838834764831845f;
}

// ===========================================================================
// K5: logits chunk: X[n].gq -> tanh clip -> mask -> exp-partial (base 10).
// grid BB*CC = 2048 (8/CU), 256 thr.
// ===========================================================================
__global__ __launch_bounds__(256, 8) void k_logits(
        const float* __restrict__ X, const float* __restrict__ gqg,
        const void* __restrict__ mask, const int* __restrict__ flag,
        float* __restrict__ lg, float* __restrict__ esumg) {
    int bid = blockIdx.x, tid = threadIdx.x;
    int b = bid >> 3, ch = bid & 7;
    const int n0 = ch * RC;
    const size_t xoff = (size_t)b * NN * DD;
    const int f = *flag;
    __shared__ float gqv[DD];
    __shared__ float redw[4];
    if (tid < DD) gqv[tid] = gqg[(size_t)b * DD + tid];
    __syncthreads();
    int g = tid & 7, r = tid >> 3;
    float esum = 0.f;
    #pragma unroll
    for (int it = 0; it < 4; ++it) {
        int nl = it * 32 + r;
        if (it < 3 || nl < RC) {
            int n = n0 + nl;
            const float4* xr = (const float4*)(X + xoff + (size_t)n * DD);
            float a = 0.f;
            #pragma unroll
            for (int i = 0; i < 4; ++i) {
                float4 v = xr[g + 8 * i];
                int col = 4 * (g + 8 * i);
                a += v.x * gqv[col] + v.y * gqv[col + 1]
                   + v.z * gqv[col + 2] + v.w * gqv[col + 3];
            }
            a += __shfl_xor(a, 1, 8);
            a += __shfl_xor(a, 2, 8);
            a += __shfl_xor(a, 4, 8);
            if (g == 0) {
                float l = 10.0f * tanhf(a);
                if (get_mask(mask, f, (size_t)b * NN + n)) l = NEG;
                lg[(size_t)b * NN + n] = l;
                esum += __expf(l - 10.0f);          // logits <= 10 always
            }
        }
    }
    #pragma unroll
    for (int off = 32; off >= 1; off >>= 1) esum += __shfl_xor(esum, off, 64);
    if ((tid & 63) == 0) redw[tid >> 6] = esum;
    __syncthreads();
    if (tid == 0) esumg[(size_t)b * CC + ch] = redw[0] + redw[1] + redw[2] + redw[3];
}

// ===========================================================================
// K6: lse + store. grid BB, 256 thr.
// ===========================================================================
__global__ __launch_bounds__(256) void k_final(
        const float* __restrict__ lg, const float* __restrict__ esumg,
        float* __restrict__ out) {
    int b = blockIdx.x, tid = threadIdx.x;
    float s = 0.f;
    #pragma unroll
    for (int ch = 0; ch < CC; ++ch) s += esumg[(size_t)b * CC + ch];
    float lse = 10.0f + logf(s);
    for (int n = tid; n < NN; n += 256)
        out[(size_t)b * NN + n] = lg[(size_t)b * NN + n] - lse;
}

// ===========================================================================
// Fallback: proven round-3 mega-kernel (fp32 path), needs no workspace.
// ===========================================================================
__global__ __launch_bounds__(1024) void k_mega(
        const float* __restrict__ X, const float* __restrict__ Wnode,
        const float* __restrict__ Wfix, const float* __restrict__ Wstep,
        const float* __restrict__ Wout, const int* __restrict__ prev,
        const int* __restrict__ first, const void* __restrict__ mask,
        float* __restrict__ out) {
    int b = blockIdx.x, tid = threadIdx.x;
    __shared__ __align__(16) float cm[HH * 1024];
    __shared__ __align__(16) float qkl[HH * DD];
    __shared__ __align__(16) float qpart[8 * DD];
    __shared__ float xa[HH * DD];
    __shared__ float ge[DD], q[DD], sc[2 * DD], hd[DD], gl[DD], gqv[DD];
    __shared__ float red[16], invh[8];
    __shared__ int s_flag;
    const size_t xoff = (size_t)b * NN * DD;

    if (tid < 64) {
        const unsigned int* mw = (const unsigned int*)mask;
        unsigned int a0 = mw[tid], a1 = mw[tid + 64], a2 = mw[tid + 128], a3 = mw[tid + 192];
        int ii = (a0 <= 1u) && (a1 <= 1u) && (a2 <= 1u) && (a3 <= 1u);
        int ff = (a0 == 0u || a0 == 0x3F800000u) && (a1 == 0u || a1 == 0x3F800000u) &&
                 (a2 == 0u || a2 == 0x3F800000u) && (a3 == 0u || a3 == 0x3F800000u);
        int ai = __all(ii), af = __all(ff);
        if (tid == 0) s_flag = ai ? 1 : (af ? 2 : 0);
    }
    if (tid >= 256 && tid < 512) {
        int t = tid - 256;
        int src = (t < DD) ? first[b] : prev[b];
        sc[t] = X[xoff + (size_t)src * DD + (t & 127)];
    }
    {
        float4* red4 = (float4*)cm;
        int c = tid & 31, s = tid >> 5;
        const float4* Xr = (const float4*)(X + xoff);
        float4 acc = make_float4(0.f, 0.f, 0.f, 0.f);
        for (int n = s; n < NN; n += 32) {
            float4 v = Xr[n * 32 + c];
            acc.x += v.x; acc.y += v.y; acc.z += v.z; acc.w += v.w;
        }
        red4[s * 32 + c] = acc;
        __syncthreads();
        for (int st = 16; st >= 1; st >>= 1) {
            if (s < st) {
                float4 o = red4[(s + st) * 32 + c];
                float4 r = red4[s * 32 + c];
                r.x += o.x; r.y += o.y; r.z += o.z; r.w += o.w;
                red4[s * 32 + c] = r;
            }
            __syncthreads();
        }
        if (s == 0) {
            float4 r = red4[c];
            ge[4 * c] = r.x * (1.0f / NN); ge[4 * c + 1] = r.y * (1.0f / NN);
            ge[4 * c + 2] = r.z * (1.0f / NN); ge[4 * c + 3] = r.w * (1.0f / NN);
        }
        __syncthreads();
    }
    const int flag = s_flag;
    {
        int p = tid >> 7, d = tid & 127;
        float a = 0.f;
        for (int k = p * 16; k < p * 16 + 16; ++k) a += ge[k] * Wfix[k * DD + d];
        for (int k = p * 32; k < p * 32 + 32; ++k) a += sc[k] * Wstep[k * DD + d];
        qpart[p * DD + d] = a;
        __syncthreads();
        if (tid < DD) {
            float s = 0.f;
            for (int pp = 0; pp < 8; ++pp) s += qpart[pp * DD + tid];
            q[tid] = s;
        }
        __syncthreads();
        int d2 = tid >> 3, h = tid & 7;
        const float4* wr = (const float4*)(Wnode + (size_t)d2 * 384 + h * 16);
        float a2 = 0.f;
        for (int j4 = 0; j4 < 4; ++j4) {
            float4 w = wr[j4];
            a2 += w.x * q[h * 16 + 4 * j4]     + w.y * q[h * 16 + 4 * j4 + 1]
                + w.z * q[h * 16 + 4 * j4 + 2] + w.w * q[h * 16 + 4 * j4 + 3];
        }
        qkl[h * DD + d2] = 0.25f * a2;
        __syncthreads();
    }
    {
        int g = tid & 7;
        for (int it = 0; it < 8; ++it) {
            int n = it * 128 + (tid >> 3);
            if (n < NN) {
                float acc[HH] = {0.f, 0.f, 0.f, 0.f, 0.f, 0.f, 0.f, 0.f};
                const float4* xr = (const float4*)(X + xoff + (size_t)n * DD);
                for (int i = 0; i < 4; ++i) {
                    float4 v = xr[g + 8 * i];
                    int col = 4 * (g + 8 * i);
                    for (int h = 0; h < HH; ++h)
                        acc[h] += v.x * qkl[h * DD + col]     + v.y * qkl[h * DD + col + 1]
                                + v.z * qkl[h * DD + col + 2] + v.w * qkl[h * DD + col + 3];
                }
                for (int h = 0; h < HH; ++h) {
                    acc[h] += __shfl_xor(acc[h], 1, 8);
                    acc[h] += __shfl_xor(acc[h], 2, 8);
                    acc[h] += __shfl_xor(acc[h], 4, 8);
                }
                float val = acc[0];
                for (int h = 1; h < HH; ++h) val = (g == h) ? acc[h] : val;
                bool mk = get_mask(mask, flag, (size_t)b * NN + n);
                cm[g * 1024 + n] = mk ? NEG : val;
            }
        }
        __syncthreads();
    }
    {
        int h = tid >> 7, lane = tid & 127;
        float mx = -INFINITY;
        for (int n = lane; n < NN; n += 128) mx = fmaxf(mx, cm[h * 1024 + n]);
        for (int off = 32; off >= 1; off >>= 1) mx = fmaxf(mx, __shfl_xor(mx, off, 64));
        if ((tid & 63) == 0) red[tid >> 6] = mx;
        __syncthreads();
        float m_h = fmaxf(red[2 * h], red[2 * h + 1]);
        float sm = 0.f;
        for (int n = lane; n < NN; n += 128) {
            float p = __expf(cm[h * 1024 + n] - m_h);
            cm[h * 1024 + n] = p;
            sm += p;
        }
        for (int off = 32; off >= 1; off >>= 1) sm += __shfl_xor(sm, off, 64);
        __syncthreads();
        if ((tid & 63) == 0) red[tid >> 6] = sm;
        __syncthreads();
        if (tid < HH) invh[tid] = 1.0f / (red[2 * tid] + red[2 * tid + 1]);
        __syncthreads();
    }
    {
        int s = tid >> 7, d = tid & 127;
        float acc[HH] = {0.f, 0.f, 0.f, 0.f, 0.f, 0.f, 0.f, 0.f};
        for (int n = s; n < NN; n += 8) {
            float x = X[xoff + (size_t)n * DD + d];
            for (int h = 0; h < HH; ++h) acc[h] += cm[h * 1024 + n] * x;
        }
        __syncthreads();
        float* xp = cm;
        for (int h = 0; h < HH; ++h) xp[(s * HH + h) * DD + d] = acc[h];
        __syncthreads();
        if (s == 0) {
            for (int h = 0; h < HH; ++h) {
                float t = 0.f;
                for (int ss = 0; ss < 8; ++ss) t += xp[(ss * HH + h) * DD + d];
                xa[h * DD + d] = t * invh[h];
            }
        }
        __syncthreads();
    }
    {
        int p = tid >> 7, t = tid & 127;
        int h = t >> 4;
        float a = 0.f;
        for (int d = p * 16; d < p * 16 + 16; ++d)
            a += xa[h * DD + d] * Wnode[(size_t)d * 384 + 128 + t];
        qpart[p * DD + t] = a;
        __syncthreads();
        if (tid < DD) {
            float s = 0.f;
            for (int pp = 0; pp < 8; ++pp) s += qpart[pp * DD + tid];
            hd[tid] = s;
        }
        __syncthreads();
        a = 0.f;
        for (int k = p * 16; k < p * 16 + 16; ++k) a += hd[k] * Wout[(size_t)k * DD + t];
        qpart[p * DD + t] = a;
        __syncthreads();
        if (tid < DD) {
            float s = 0.f;
            for (int pp = 0; pp < 8; ++pp) s += qpart[pp * DD + tid];
            gl[tid] = s;
        }
        __syncthreads();
        const float4* wr = (const float4*)(Wnode + (size_t)t * 384 + 256 + p * 16);
        a = 0.f;
        for (int j4 = 0; j4 < 4; ++j4) {
            float4 w = wr[j4];
            int k = p * 16 + 4 * j4;
            a += w.x * gl[k] + w.y * gl[k + 1] + w.z * gl[k + 2] + w.w * gl[k + 3];
        }
        qpart[p * DD + t] = a;
        __syncthreads();
        if (tid < DD) {
            float s = 0.f;
            for (int pp = 0; pp < 8; ++pp) s += qpart[pp * DD + tid];
            gqv[tid] = s * 0.08838834764831845f;
        }
        __syncthreads();
    }
    {
        float* lg = qkl;
        int g = tid & 7;
        for (int it = 0; it < 8; ++it) {
            int n = it * 128 + (tid >> 3);
            if (n < NN) {
                const float4* xr = (const float4*)(X + xoff + (size_t)n * DD);
                float a = 0.f;
                for (int i = 0; i < 4; ++i) {
                    float4 v = xr[g + 8 * i];
                    int col = 4 * (g + 8 * i);
                    a += v.x * gqv[col] + v.y * gqv[col + 1] + v.z * gqv[col + 2] + v.w * gqv[col + 3];
                }
                a += __shfl_xor(a, 1, 8);
                a += __shfl_xor(a, 2, 8);
                a += __shfl_xor(a, 4, 8);
                if (g == 0) {
                    float lgt = 10.0f * tanhf(a);
                    lg[n] = get_mask(mask, flag, (size_t)b * NN + n) ? NEG : lgt;
                }
            }
        }
        __syncthreads();
        float v = (tid < NN) ? lg[tid] : -INFINITY;
        float mx = v;
        for (int off = 32; off >= 1; off >>= 1) mx = fmaxf(mx, __shfl_xor(mx, off, 64));
        if ((tid & 63) == 0) red[tid >> 6] = mx;
        __syncthreads();
        float m = red[0];
        for (int w = 1; w < 16; ++w) m = fmaxf(m, red[w]);
        float e = (tid < NN) ? __expf(v - m) : 0.f;
        float sm = e;
        for (int off = 32; off >= 1; off >>= 1) sm += __shfl_xor(sm, off, 64);
        __syncthreads();
        if ((tid & 63) == 0) red[tid >> 6] = sm;
        __syncthreads();
        float s2 = 0.f;
        for (int w = 0; w < 16; ++w) s2 += red[w];
        float lse = m + logf(s2);
        if (tid < NN) out[(size_t)b * NN + tid] = v - lse;
    }
}

// ---------------------------------------------------------------------------
extern "C" void kernel_launch(void* const* d_in, const int* in_sizes, int n_in,
                              void* d_out, int out_size, void* d_ws, size_t ws_size,
                              hipStream_t stream) {
    const float* X     = (const float*)d_in[0];
    const float* Wnode = (const float*)d_in[1];
    const float* Wfix  = (const float*)d_in[2];
    const float* Wstep = (const float*)d_in[3];
    const float* Wout  = (const float*)d_in[4];
    const int*   prev  = (const int*)d_in[5];
    const int*   first = (const int*)d_in[6];
    const void*  mask  = d_in[7];
    float* out = (float*)d_out;

    char* wsb = (char*)d_ws;
    int*   flag    = (int*)wsb;
    float* base    = (float*)(wsb + 256);
    float* partial = base;                                   // B*C*D   = 262144
    float* qkg     = partial + (size_t)BB * CC * DD;         // B*H*D   = 262144
    float* mqw     = qkg + (size_t)BB * HH * DD;             // B*C*H   = 16384
    float* sqw     = mqw + (size_t)BB * CC * HH;             // 16384
    float* pvp     = sqw + (size_t)BB * CC * HH;             // B*C*H*D = 2097152
    float* gqg     = pvp + (size_t)BB * CC * HH * DD;        // B*D     = 32768
    float* esumg   = gqg + (size_t)BB * DD;                  // B*C     = 2048
    float* lg      = esumg + (size_t)BB * CC;                // B*N     = 256000
    const size_t need = 256 + sizeof(float) * (
        (size_t)BB * CC * DD + (size_t)BB * HH * DD + 2 * (size_t)BB * CC * HH +
        (size_t)BB * CC * HH * DD + (size_t)BB * DD + (size_t)BB * CC + (size_t)BB * NN);

    if (ws_size >= need) {
        k_mean  <<<BB * CC, 256, 0, stream>>>(X, partial, (const unsigned int*)mask, flag);
        k_qk    <<<BB, 256, 0, stream>>>(X, Wfix, Wstep, Wnode, partial, prev, first, qkg);
        k_flash <<<BB * CC, 256, 0, stream>>>(X, qkg, mask, flag, mqw, sqw, pvp);
        k_comb  <<<BB, 256, 0, stream>>>(Wnode, Wout, mqw, sqw, pvp, gqg);
        k_logits<<<BB * CC, 256, 0, stream>>>(X, gqg, mask, flag, lg, esumg);
        k_final <<<BB, 256, 0, stream>>>(lg, esumg, out);
    } else {
        k_mega<<<BB, 1024, 0, stream>>>(X, Wnode, Wfix, Wstep, Wout,
                                        prev, first, mask, out);
    }
}